// Round 1
// baseline (443.349 us; speedup 1.0000x reference)
//
#include <hip/hip_runtime.h>
#include <hip/hip_fp16.h>

#define B_SZ  512
#define S_LEN 512
#define D_IN  64
#define H_DIM 32

// fast sigmoid / tanh via v_exp_f32 (base-2) + v_rcp_f32.
// Saturation behavior is safe: exp2(+inf)->inf, rcp(inf)->0.
__device__ __forceinline__ float fsig(float x) {
    float e = __builtin_amdgcn_exp2f(x * -1.44269504088896340736f);
    return __builtin_amdgcn_rcpf(1.0f + e);
}
__device__ __forceinline__ float ftanh(float x) {
    float e = __builtin_amdgcn_exp2f(x * -2.88539008177792681472f);
    return __builtin_fmaf(2.0f, __builtin_amdgcn_rcpf(1.0f + e), -1.0f);
}

// ---------------------------------------------------------------------------
// Kernel 1: gx[row][n] = sum_k x[row][k]*Wih0[n][k] + bih0[n] + bhh0[n]
// rows = b*S+t (262144), n in [0,128), k in [0,64). Output fp16.
// Block: 256 threads, 64 rows x 128 cols per block. Grid: 4096.
// ---------------------------------------------------------------------------
__global__ __launch_bounds__(256) void xproj_kernel(
    const float* __restrict__ x,
    const float* __restrict__ Wih0,
    const float* __restrict__ bih0,
    const float* __restrict__ bhh0,
    __half* __restrict__ gxh)
{
    __shared__ float xs[64][66];    // pad 66: read bank = (2r+k)%32 -> 4-way max
    __shared__ float wt[64][132];   // Wih0 transposed, pad 132 keeps 16B align

    const int tid = threadIdx.x;
    const size_t row0 = (size_t)blockIdx.x * 64;

    // stage Wih0^T : Wih0 is [128][64] = 2048 float4
    #pragma unroll
    for (int i = 0; i < 8; ++i) {
        int f4 = tid + i * 256;
        int n  = f4 >> 4;
        int k4 = (f4 & 15) << 2;
        float4 v = reinterpret_cast<const float4*>(Wih0)[f4];
        wt[k4 + 0][n] = v.x;
        wt[k4 + 1][n] = v.y;
        wt[k4 + 2][n] = v.z;
        wt[k4 + 3][n] = v.w;
    }
    // stage 64 rows of x : 1024 float4
    #pragma unroll
    for (int i = 0; i < 4; ++i) {
        int f4 = tid + i * 256;
        int r  = f4 >> 4;
        int k4 = (f4 & 15) << 2;
        float4 v = reinterpret_cast<const float4*>(x + row0 * D_IN)[f4];
        xs[r][k4 + 0] = v.x;
        xs[r][k4 + 1] = v.y;
        xs[r][k4 + 2] = v.z;
        xs[r][k4 + 3] = v.w;
    }
    __syncthreads();

    const int cg = tid & 15;    // 16 col groups * 8 cols
    const int rg = tid >> 4;    // 16 row groups * 4 rows
    const int n0 = cg << 3;
    const int r0 = rg << 2;

    float acc[4][8];
    #pragma unroll
    for (int c = 0; c < 8; ++c) {
        float bb = bih0[n0 + c] + bhh0[n0 + c];
        #pragma unroll
        for (int r = 0; r < 4; ++r) acc[r][c] = bb;
    }

    #pragma unroll 4
    for (int k = 0; k < 64; ++k) {
        const float4 wa = *reinterpret_cast<const float4*>(&wt[k][n0]);
        const float4 wb = *reinterpret_cast<const float4*>(&wt[k][n0 + 4]);
        float wv[8] = {wa.x, wa.y, wa.z, wa.w, wb.x, wb.y, wb.z, wb.w};
        float xv[4];
        #pragma unroll
        for (int r = 0; r < 4; ++r) xv[r] = xs[r0 + r][k];
        #pragma unroll
        for (int r = 0; r < 4; ++r)
            #pragma unroll
            for (int c = 0; c < 8; ++c)
                acc[r][c] = __builtin_fmaf(xv[r], wv[c], acc[r][c]);
    }

    #pragma unroll
    for (int r = 0; r < 4; ++r) {
        size_t row = row0 + r0 + r;
        __half2* dst = reinterpret_cast<__half2*>(gxh + row * 128 + n0);
        dst[0] = __floats2half2_rn(acc[r][0], acc[r][1]);
        dst[1] = __floats2half2_rn(acc[r][2], acc[r][3]);
        dst[2] = __floats2half2_rn(acc[r][4], acc[r][5]);
        dst[3] = __floats2half2_rn(acc[r][6], acc[r][7]);
    }
}

// ---------------------------------------------------------------------------
// Kernel 2: fused 2-layer LSTM scan + FC epilogue.
// Block = 256 threads (4 waves), owns 2 batch rows.
//   wave id = gate g (i,f,g,o); lane = (bl = batch local, j = h index).
// Recurrent weights (3 x 32 fp32) live in VGPRs per lane.
// 4 barriers / timestep: act0, h0, act1, h1.
// ---------------------------------------------------------------------------
__global__ __launch_bounds__(256) void lstm_scan_kernel(
    const __half* __restrict__ gxh,
    const float* __restrict__ Whh0,
    const float* __restrict__ Wih1,
    const float* __restrict__ Whh1,
    const float* __restrict__ bih1,
    const float* __restrict__ bhh1,
    const float* __restrict__ Wfc,
    const float* __restrict__ bfc,
    float* __restrict__ out)
{
    const int tid  = threadIdx.x;
    const int g    = tid >> 6;        // wave = gate
    const int lane = tid & 63;
    const int bl   = lane >> 5;
    const int j    = lane & 31;
    const int n    = (g << 5) | j;    // gate row in [0,128)
    const int b    = (blockIdx.x << 1) | bl;

    __shared__ float act[2][32][4];   // [bl][j][gate]
    __shared__ float h0s[2][32];
    __shared__ float h1s[2][32];

    float w0[32], wi1[32], wh1[32];
    #pragma unroll
    for (int k4 = 0; k4 < 8; ++k4) {
        float4 v0 = reinterpret_cast<const float4*>(Whh0)[n * 8 + k4];
        w0 [4*k4+0] = v0.x; w0 [4*k4+1] = v0.y; w0 [4*k4+2] = v0.z; w0 [4*k4+3] = v0.w;
        float4 v1 = reinterpret_cast<const float4*>(Wih1)[n * 8 + k4];
        wi1[4*k4+0] = v1.x; wi1[4*k4+1] = v1.y; wi1[4*k4+2] = v1.z; wi1[4*k4+3] = v1.w;
        float4 v2 = reinterpret_cast<const float4*>(Whh1)[n * 8 + k4];
        wh1[4*k4+0] = v2.x; wh1[4*k4+1] = v2.y; wh1[4*k4+2] = v2.z; wh1[4*k4+3] = v2.w;
    }
    const float bias1 = bih1[n] + bhh1[n];

    float h0v[32], h1v[32];
    #pragma unroll
    for (int k = 0; k < 32; ++k) { h0v[k] = 0.f; h1v[k] = 0.f; }
    float c0 = 0.f, c1 = 0.f;

    const __half* gp = gxh + ((size_t)b * S_LEN) * 128 + n;
    float gcur = __half2float(gp[0]);

    for (int t = 0; t < S_LEN; ++t) {
        float gnext = 0.f;
        if (t + 1 < S_LEN) gnext = __half2float(gp[(size_t)(t + 1) * 128]);

        // ---- layer 0, gate n: gx + h0 . Whh0[n,:]
        float a0 = gcur, a1 = 0.f, a2 = 0.f, a3 = 0.f;
        #pragma unroll
        for (int k = 0; k < 32; k += 4) {
            a0 = __builtin_fmaf(h0v[k+0], w0[k+0], a0);
            a1 = __builtin_fmaf(h0v[k+1], w0[k+1], a1);
            a2 = __builtin_fmaf(h0v[k+2], w0[k+2], a2);
            a3 = __builtin_fmaf(h0v[k+3], w0[k+3], a3);
        }
        float r0 = (a0 + a1) + (a2 + a3);
        act[bl][j][g] = (g == 2) ? ftanh(r0) : fsig(r0);   // wave-uniform select
        __syncthreads();

        float4 ga = *reinterpret_cast<const float4*>(&act[bl][j][0]);
        c0 = __builtin_fmaf(ga.y, c0, ga.x * ga.z);        // f*c + i*g (replicated x4 waves)
        float h0n = ga.w * ftanh(c0);
        if (g == 0) h0s[bl][j] = h0n;
        __syncthreads();

        #pragma unroll
        for (int k4 = 0; k4 < 8; ++k4) {
            float4 v = *reinterpret_cast<const float4*>(&h0s[bl][k4 << 2]);
            h0v[4*k4+0] = v.x; h0v[4*k4+1] = v.y; h0v[4*k4+2] = v.z; h0v[4*k4+3] = v.w;
        }

        // ---- layer 1, gate n: bias1 + h0 . Wih1[n,:] + h1 . Whh1[n,:]
        float b0 = bias1, b1 = 0.f, b2 = 0.f, b3 = 0.f;
        #pragma unroll
        for (int k = 0; k < 32; k += 4) {
            b0 = __builtin_fmaf(h0v[k+0], wi1[k+0], b0);
            b1 = __builtin_fmaf(h0v[k+1], wi1[k+1], b1);
            b2 = __builtin_fmaf(h0v[k+2], wi1[k+2], b2);
            b3 = __builtin_fmaf(h0v[k+3], wi1[k+3], b3);
        }
        #pragma unroll
        for (int k = 0; k < 32; k += 4) {
            b0 = __builtin_fmaf(h1v[k+0], wh1[k+0], b0);
            b1 = __builtin_fmaf(h1v[k+1], wh1[k+1], b1);
            b2 = __builtin_fmaf(h1v[k+2], wh1[k+2], b2);
            b3 = __builtin_fmaf(h1v[k+3], wh1[k+3], b3);
        }
        float r1 = (b0 + b1) + (b2 + b3);
        act[bl][j][g] = (g == 2) ? ftanh(r1) : fsig(r1);
        __syncthreads();

        float4 gb = *reinterpret_cast<const float4*>(&act[bl][j][0]);
        c1 = __builtin_fmaf(gb.y, c1, gb.x * gb.z);
        float h1n = gb.w * ftanh(c1);
        if (g == 0) h1s[bl][j] = h1n;
        __syncthreads();

        #pragma unroll
        for (int k4 = 0; k4 < 8; ++k4) {
            float4 v = *reinterpret_cast<const float4*>(&h1s[bl][k4 << 2]);
            h1v[4*k4+0] = v.x; h1v[4*k4+1] = v.y; h1v[4*k4+2] = v.z; h1v[4*k4+3] = v.w;
        }

        gcur = gnext;
    }

    // FC epilogue: out[b] = h1_final . Wfc + bfc (every lane holds full h1v)
    if (tid == 0 || tid == 32) {
        float s = bfc[0];
        #pragma unroll
        for (int k = 0; k < 32; ++k) s = __builtin_fmaf(h1v[k], Wfc[k], s);
        out[b] = s;
    }
}

extern "C" void kernel_launch(void* const* d_in, const int* in_sizes, int n_in,
                              void* d_out, int out_size, void* d_ws, size_t ws_size,
                              hipStream_t stream) {
    (void)in_sizes; (void)n_in; (void)out_size;
    const float* x    = (const float*)d_in[0];
    const float* Wih0 = (const float*)d_in[1];
    const float* Whh0 = (const float*)d_in[2];
    const float* bih0 = (const float*)d_in[3];
    const float* bhh0 = (const float*)d_in[4];
    const float* Wih1 = (const float*)d_in[5];
    const float* Whh1 = (const float*)d_in[6];
    const float* bih1 = (const float*)d_in[7];
    const float* bhh1 = (const float*)d_in[8];
    const float* Wfc  = (const float*)d_in[9];
    const float* bfc  = (const float*)d_in[10];
    float* out = (float*)d_out;

    const size_t need = (size_t)B_SZ * S_LEN * 128 * sizeof(__half);  // 64 MB
    if (ws_size < need) return;  // ws too small -> clean validation failure, no OOB
    __half* gxh = (__half*)d_ws;

    hipLaunchKernelGGL(xproj_kernel, dim3((B_SZ * S_LEN) / 64), dim3(256), 0, stream,
                       x, Wih0, bih0, bhh0, gxh);
    hipLaunchKernelGGL(lstm_scan_kernel, dim3(B_SZ / 2), dim3(256), 0, stream,
                       gxh, Whh0, Wih1, Whh1, bih1, bhh1, Wfc, bfc, out);
}